// Round 1
// baseline (185.926 us; speedup 1.0000x reference)
//
#include <hip/hip_runtime.h>

typedef __bf16 bf16x8 __attribute__((ext_vector_type(8)));
typedef __bf16 bf16x4 __attribute__((ext_vector_type(4)));
typedef float  f32x4  __attribute__((ext_vector_type(4)));

#define MFMA(a, b, c) __builtin_amdgcn_mfma_f32_16x16x32_bf16((a), (b), (c), 0, 0, 0)
// explicit DMA drain: vmcnt(0), leave expcnt/lgkmcnt unwaited (gfx9 encoding)
#define DRAIN_VMCNT() __builtin_amdgcn_s_waitcnt(0x0F70)

constexpr int Bc  = 8;
constexpr int D   = 256;
constexpr int TC  = 2048;
constexpr int TE  = 2048;
constexpr int TGT = 256;
constexpr int XR  = 512;            // xcat row stride (2D)
constexpr int CROW = 520;           // conv LDS row stride (bf16)
constexpr int NBT = Bc * TC;        // 16384 rows

// exp(x/16) == exp2(x * log2(e)/16); fold the 1/SCALE into the exp2 constant
#define EXP_C 0.09016844005556021f

// async global->LDS, 16B per lane; LDS dst = base + lane*16 (wave-uniform base)
__device__ __forceinline__ void gl_lds16(const __bf16* g, __bf16* l) {
  __builtin_amdgcn_global_load_lds(
      (const __attribute__((address_space(1))) void*)g,
      (__attribute__((address_space(3))) void*)l, 16, 0, 0);
}

// ---- transpose+cast: src fp32 [B][256][T] -> dst bf16 [B][T][rowStride] ----
// load side: float4 (16B/lane). store side: bf16x8 (16B/lane) -- G13 both ways.
__global__ void k_transpose_f(const float* __restrict__ src, __bf16* __restrict__ dst,
                              int T, int rowStride) {
  __shared__ __bf16 tile[64][68];
  const int b  = blockIdx.z;
  const int t0 = blockIdx.x * 64;
  const int d0 = blockIdx.y * 64;
  const int tid = threadIdx.x;
  const int c4 = (tid & 15) * 4;
  const int r0 = tid >> 4;          // 0..15
  const float* sp = src + ((size_t)b * D + d0) * T + t0;
#pragma unroll
  for (int i = 0; i < 4; ++i) {
    const int r = r0 + 16 * i;
    const float4 v = *(const float4*)(sp + (size_t)r * T + c4);
    bf16x4 wv;
    wv[0] = (__bf16)v.x; wv[1] = (__bf16)v.y; wv[2] = (__bf16)v.z; wv[3] = (__bf16)v.w;
    *(bf16x4*)&tile[r][c4] = wv;
  }
  __syncthreads();
  // tile[d][t] -> dst rows t, 8 d per lane, 16B stores, fully coalesced per wave
  __bf16* dp = dst + ((size_t)b * T + t0) * rowStride + d0;
#pragma unroll
  for (int i = 0; i < 2; ++i) {
    const int idx = tid + 256 * i;  // 0..511
    const int r   = idx >> 3;       // output row (t-local) 0..63
    const int c8  = (idx & 7) * 8;  // output col block (d-local)
    bf16x8 v;
#pragma unroll
    for (int j = 0; j < 8; ++j) v[j] = tile[c8 + j][r];
    *(bf16x8*)(dp + (size_t)r * rowStride + c8) = v;
  }
}

// ---- fused emotion prep: fp32 [B][D][TE] -> bf16 e_t [B][TE][D] + e_ds [B][D][TE]
__global__ void k_prep_emo(const float* __restrict__ src, __bf16* __restrict__ e_t,
                           __bf16* __restrict__ e_ds) {
  __shared__ __bf16 tile[64][68];
  const int b  = blockIdx.z;
  const int t0 = blockIdx.x * 64;
  const int d0 = blockIdx.y * 64;
  const int tid = threadIdx.x;
  const int c4 = (tid & 15) * 4;
  const int r0 = tid >> 4;
  const float* sp = src + ((size_t)b * D + d0) * TE + t0;
  __bf16* dsp = e_ds + ((size_t)b * D + d0) * TE + t0;
#pragma unroll
  for (int i = 0; i < 4; ++i) {
    const int r = r0 + 16 * i;
    const float4 v = *(const float4*)(sp + (size_t)r * TE + c4);
    bf16x4 wv;
    wv[0] = (__bf16)v.x; wv[1] = (__bf16)v.y; wv[2] = (__bf16)v.z; wv[3] = (__bf16)v.w;
    *(bf16x4*)&tile[r][c4] = wv;
    *(bf16x4*)(dsp + (size_t)r * TE + c4) = wv;
  }
  __syncthreads();
  __bf16* dp = e_t + ((size_t)b * TE + t0) * D + d0;
#pragma unroll
  for (int i = 0; i < 2; ++i) {
    const int idx = tid + 256 * i;
    const int r   = idx >> 3;
    const int c8  = (idx & 7) * 8;
    bf16x8 v;
#pragma unroll
    for (int j = 0; j < 8; ++j) v[j] = tile[c8 + j][r];
    *(bf16x8*)(dp + (size_t)r * D + c8) = v;
  }
}

// ---- conv weight repack+cast: w fp32 [256][512][3] -> Wk bf16 [3][256][512] ----
__global__ void k_wpack_f(const float* __restrict__ w, __bf16* __restrict__ Wk) {
  const int idx = blockIdx.x * 256 + threadIdx.x;  // o*512 + i
  const int o = idx >> 9, i = idx & 511;
#pragma unroll
  for (int k = 0; k < 3; ++k)
    Wk[k * (TGT * 512) + idx] = (__bf16)w[(size_t)o * 1536 + i * 3 + k];
}

// ---- flash attention: 128 t x 4 waves (Tw=32), z=4 s-split, dbuf shared tiles ----
// All 4 waves consume the SAME 32-s tile pair; stage(k+1) issued before compute(k);
// vmcnt(0) drain at step end (issued a compute-phase ago -> hidden). Writes
// UNNORMALIZED bf16 partial O + fp32 partial L per z-chunk.
__global__ __launch_bounds__(256, 2) void k_attn(const __bf16* __restrict__ xcat,
                                                 const __bf16* __restrict__ e_t,
                                                 const __bf16* __restrict__ e_ds,
                                                 __bf16* __restrict__ Op,
                                                 float* __restrict__ Lp) {
  __shared__ __align__(16) __bf16 sEt[2][8192];   // [buf]: row ss, chunk cs -> c=cs^(ss&7)
  __shared__ __align__(16) __bf16 sEs[2][8192];   // [buf]: row dd, slot ps -> p=ps^((dd>>2)&3)
  __shared__ __align__(16) __bf16 sP[4][2][640];  // per-wave P transpose, stride 40

  const int tid  = threadIdx.x;
  const int lane = tid & 63;
  const int w    = tid >> 6;        // 0..3 -> 32-t group
  const int q    = lane >> 4;
  const int tl   = lane & 15;
  const int b    = blockIdx.y;
  const int z    = blockIdx.z;      // s-quarter
  const int tbase = blockIdx.x * 128 + w * 32;

  const __bf16* etb = e_t  + (size_t)b * TE * D;   // [TE][D]
  const __bf16* esb = e_ds + (size_t)b * D * TE;   // [D][TE]

  // loop-invariant query fragments (B-operand of phase 1), 2 t-tiles
  bf16x8 cB[2][8];
#pragma unroll
  for (int tt = 0; tt < 2; ++tt) {
    const __bf16* crow = xcat + ((size_t)(b * TC) + tbase + tt * 16 + tl) * XR + q * 8;
#pragma unroll
    for (int ks = 0; ks < 8; ++ks) cB[tt][ks] = *(const bf16x8*)(crow + ks * 32);
  }

  // per-lane swizzled staging offsets; each wave stages 1/4 of each tile kind
  unsigned offEt[4], offEs[4];
#pragma unroll
  for (int c = 0; c < 4; ++c) {
    const int id = (w * 4 + c) * 64 + lane;        // 0..1023
    const int ss = id >> 5, cs = id & 31;
    offEt[c] = ss * D + (cs ^ (ss & 7)) * 8;       // row-contig global, swizzled chunk
    const int dd = id >> 2, ps = id & 3;
    offEs[c] = dd * TE + (ps ^ ((dd >> 2) & 3)) * 8;
  }

  f32x4 accO[2][16];
#pragma unroll
  for (int tt = 0; tt < 2; ++tt)
#pragma unroll
    for (int dt = 0; dt < 16; ++dt) accO[tt][dt] = (f32x4){0.f, 0.f, 0.f, 0.f};
  float lacc[2] = {0.f, 0.f};

  const int sbase = z * (TE / 4);
  const int sw3 = (tl >> 2) & 3;    // sEs read swizzle term

  auto stage = [&](int buf, int s0) {
#pragma unroll
    for (int c = 0; c < 4; ++c) {
      gl_lds16(etb + (size_t)s0 * D + offEt[c], &sEt[buf][(w * 4 + c) * 512]);
      gl_lds16(esb + s0 + offEs[c], &sEs[buf][(w * 4 + c) * 512]);
    }
  };

  stage(0, sbase);
  DRAIN_VMCNT();
  __syncthreads();

  int cur = 0;
  for (int k = 0; k < TE / 128; ++k) {   // 16 steps of 32 s
    if (k < TE / 128 - 1) stage(cur ^ 1, sbase + (k + 1) * 32);  // prefetch, in flight

    // ---- phase 1: S^T for 32 s x 32 t ----
    f32x4 aS[2][2];
#pragma unroll
    for (int i = 0; i < 2; ++i)
#pragma unroll
      for (int j = 0; j < 2; ++j) aS[i][j] = (f32x4){0.f, 0.f, 0.f, 0.f};
    const __bf16* pe = &sEt[cur][0];
    __builtin_amdgcn_s_setprio(1);
#pragma unroll
    for (int ks = 0; ks < 8; ++ks) {
      const int ch = (ks * 4 + q) ^ (tl & 7);
      bf16x8 a0 = *(const bf16x8*)(pe + (tl * 32 + ch) * 8);
      bf16x8 a1 = *(const bf16x8*)(pe + ((16 + tl) * 32 + ch) * 8);
      aS[0][0] = MFMA(a0, cB[0][ks], aS[0][0]);
      aS[0][1] = MFMA(a0, cB[1][ks], aS[0][1]);
      aS[1][0] = MFMA(a1, cB[0][ks], aS[1][0]);
      aS[1][1] = MFMA(a1, cB[1][ks], aS[1][1]);
    }
    __builtin_amdgcn_s_setprio(0);

    // ---- exp + pack bf16, C-layout -> per-wave LDS transpose ----
#pragma unroll
    for (int tt = 0; tt < 2; ++tt) {
      bf16x4 w0, w1;
#pragma unroll
      for (int r = 0; r < 4; ++r) {
        float e0 = exp2f(aS[0][tt][r] * EXP_C);
        float e1 = exp2f(aS[1][tt][r] * EXP_C);
        lacc[tt] += e0 + e1;
        w0[r] = (__bf16)e0;
        w1[r] = (__bf16)e1;
      }
      __bf16* pw = &sP[w][tt][tl * 40 + q * 4];
      *(bf16x4*)pw = w0;          // P[s=q*4+r][t=tl]
      *(bf16x4*)(pw + 16) = w1;   // P[s=16+q*4+r][t=tl]
    }
    bf16x8 pB0 = *(const bf16x8*)(&sP[w][0][tl * 40 + q * 8]);
    bf16x8 pB1 = *(const bf16x8*)(&sP[w][1][tl * 40 + q * 8]);

    // ---- phase 2: O^T accumulate, 16 d-tiles, A-frag shared by both t-tiles ----
    const __bf16* ps = &sEs[cur][0];
    __builtin_amdgcn_s_setprio(1);
#pragma unroll
    for (int dt = 0; dt < 16; ++dt) {
      bf16x8 a = *(const bf16x8*)(ps + ((dt * 16 + tl) * 4 + (q ^ sw3)) * 8);
      accO[0][dt] = MFMA(a, pB0, accO[0][dt]);
      accO[1][dt] = MFMA(a, pB1, accO[1][dt]);
    }
    __builtin_amdgcn_s_setprio(0);

    DRAIN_VMCNT();     // prefetch (issued before compute) must have landed
    __syncthreads();   // + all waves done reading tile k before overwrite
    cur ^= 1;
  }

  // ---- per-wave epilogue: no cross-wave merge (wave owns its 32 t) ----
#pragma unroll
  for (int tt = 0; tt < 2; ++tt) {
    float v = lacc[tt];
    v += __shfl_xor(v, 16, 64);
    v += __shfl_xor(v, 32, 64);
    const size_t row = (size_t)z * NBT + b * TC + tbase + tt * 16 + tl;
    if (q == 0) Lp[row] = v;
    __bf16* orow = Op + row * D + q * 4;
#pragma unroll
    for (int dt = 0; dt < 16; ++dt) {
      bf16x4 o;
#pragma unroll
      for (int r = 0; r < 4; ++r) o[r] = (__bf16)accO[tt][dt][r];
      *(bf16x4*)(orow + dt * 16) = o;
    }
  }
}

// ---- combine 4 z-partials, normalize, write bf16 into xcat[..][256:512] ----
__global__ void k_norm(const __bf16* __restrict__ Op, const float* __restrict__ Lp,
                       __bf16* __restrict__ xcat) {
  const int row  = blockIdx.x * 4 + (threadIdx.x >> 6);
  const int lane = threadIdx.x & 63;
  float lsum = 0.f;
#pragma unroll
  for (int zz = 0; zz < 4; ++zz) lsum += Lp[zz * NBT + row];
  const float inv = 1.0f / lsum;
  float acc[4] = {0.f, 0.f, 0.f, 0.f};
#pragma unroll
  for (int zz = 0; zz < 4; ++zz) {
    bf16x4 a = *(const bf16x4*)(Op + ((size_t)zz * NBT + row) * D + lane * 4);
#pragma unroll
    for (int r = 0; r < 4; ++r) acc[r] += (float)a[r];
  }
  bf16x4 o;
#pragma unroll
  for (int r = 0; r < 4; ++r) o[r] = (__bf16)(acc[r] * inv);
  *(bf16x4*)(xcat + (size_t)row * XR + D + lane * 4) = o;
}

// ---- conv1d as LDS-staged 3-tap GEMM: 32 t x 256 o, grid 512, 2 blocks/CU ----
__global__ __launch_bounds__(256, 2) void k_conv(const __bf16* __restrict__ xcat,
                                                 const __bf16* __restrict__ Wk,
                                                 const float* __restrict__ bias,
                                                 float* __restrict__ out) {
  __shared__ __align__(16) __bf16 sX[34 * CROW];   // rows t0-1 .. t0+32
  __shared__ __align__(16) __bf16 sW[2][8192];     // row o, slot ps -> p=ps^((o>>2)&3)
  const int tid  = threadIdx.x;
  const int lane = tid & 63;
  const int wv   = tid >> 6;        // wave -> o-range (64 o each)
  const int q    = lane >> 4;
  const int tl   = lane & 15;
  const int b    = blockIdx.x & 7;
  const int t0   = (blockIdx.x >> 3) * 32;
  const int o0   = wv * 64;
  const int sw3  = (tl >> 2) & 3;

  // stage 34 xcat rows (coalesced full rows; halo rows zeroed below)
  const __bf16* xb = xcat + (size_t)b * TC * XR;
  for (int r = wv; r < 34; r += 4) {
    int gr = t0 - 1 + r;
    gr = gr < 0 ? 0 : (gr > TC - 1 ? TC - 1 : gr);
    gl_lds16(xb + (size_t)gr * XR + lane * 8, &sX[r * CROW]);
  }

  // swizzled per-lane weight offsets: 4 calls per wave, 64B-coalesced per o-row
  unsigned offW[4];
#pragma unroll
  for (int c = 0; c < 4; ++c) {
    const int id = (wv * 4 + c) * 64 + lane;       // 0..1023
    const int o = id >> 2, ps = id & 3;
    offW[c] = o * 512 + (ps ^ ((o >> 2) & 3)) * 8;
  }
  auto stageW = [&](int buf, int s) {
    const int kk = s >> 4, is = s & 15;
    const __bf16* wb = Wk + (size_t)kk * TGT * 512 + is * 32;
#pragma unroll
    for (int c = 0; c < 4; ++c)
      gl_lds16(wb + offW[c], &sW[buf][(wv * 4 + c) * 512]);
  };
  stageW(0, 0);
  DRAIN_VMCNT();                    // sX + sW(0) DMA must land before reads/overwrites
  __syncthreads();
  if (t0 == 0)       for (int i = tid; i < CROW; i += 256) sX[i] = (__bf16)0.f;
  if (t0 + 32 == TC) for (int i = tid; i < CROW; i += 256) sX[33 * CROW + i] = (__bf16)0.f;
  __syncthreads();

  f32x4 acc[4][2];
#pragma unroll
  for (int mt = 0; mt < 4; ++mt) {
#pragma unroll
    for (int r = 0; r < 4; ++r) {
      const float bv = bias[o0 + mt * 16 + q * 4 + r];
#pragma unroll
      for (int nt = 0; nt < 2; ++nt) acc[mt][nt][r] = bv;
    }
  }

  int cur = 0;
  for (int s = 0; s < 48; ++s) {
    if (s < 47) stageW(cur ^ 1, s + 1);
    const int kk = s >> 4, is = s & 15;
    bf16x8 bfr[2];
#pragma unroll
    for (int nt = 0; nt < 2; ++nt)
      bfr[nt] = *(const bf16x8*)(&sX[(nt * 16 + tl + kk) * CROW + is * 32 + q * 8]);
    __builtin_amdgcn_s_setprio(1);
#pragma unroll
    for (int mt = 0; mt < 4; ++mt) {
      const int o = o0 + mt * 16 + tl;
      bf16x8 af = *(const bf16x8*)(&sW[cur][(o * 4 + (q ^ sw3)) * 8]);
#pragma unroll
      for (int nt = 0; nt < 2; ++nt) acc[mt][nt] = MFMA(af, bfr[nt], acc[mt][nt]);
    }
    __builtin_amdgcn_s_setprio(0);
    DRAIN_VMCNT();                  // next weight tile landed before buffer swap
    __syncthreads();
    cur ^= 1;
  }

#pragma unroll
  for (int mt = 0; mt < 4; ++mt) {
#pragma unroll
    for (int nt = 0; nt < 2; ++nt) {
#pragma unroll
      for (int r = 0; r < 4; ++r) {
        const int o = o0 + mt * 16 + q * 4 + r;
        const int t = t0 + nt * 16 + tl;
        out[((size_t)b * TGT + o) * TC + t] = acc[mt][nt][r];
      }
    }
  }
}

extern "C" void kernel_launch(void* const* d_in, const int* in_sizes, int n_in,
                              void* d_out, int out_size, void* d_ws, size_t ws_size,
                              hipStream_t stream) {
  (void)in_sizes; (void)n_in; (void)out_size; (void)ws_size;
  const float* content = (const float*)d_in[0];  // fp32 [B][256][2048]
  const float* emotion = (const float*)d_in[1];  // fp32 [B][256][2048]
  const float* conv_w  = (const float*)d_in[2];  // fp32 [256][512][3]
  const float* conv_b  = (const float*)d_in[3];  // fp32 [256]
  float* out = (float*)d_out;                    // fp32 [B][256][2048]

  char* ws = (char*)d_ws;
  __bf16* xcat = (__bf16*)ws;                          // 16,777,216 B
  __bf16* Wk   = (__bf16*)(ws + 16777216);             //    786,432 B
  __bf16* Op   = (__bf16*)(ws + 17563648);             // 33,554,432 B (4 z-partials)
  float*  Lp   = (float*)(ws + 51118080);              //    262,144 B (total 49.0 MB)
  // e_t + e_ds live in d_out (8,388,608 B each); consumed before k_conv writes out.
  __bf16* e_t  = (__bf16*)d_out;                       // bf16 [B][TE][D]
  __bf16* e_ds = (__bf16*)((char*)d_out + 8388608);    // bf16 [B][D][TE]

  k_transpose_f<<<dim3(TC / 64, D / 64, Bc), 256, 0, stream>>>(content, xcat, TC, XR);
  k_prep_emo<<<dim3(TE / 64, D / 64, Bc), 256, 0, stream>>>(emotion, e_t, e_ds);
  k_wpack_f<<<512, 256, 0, stream>>>(conv_w, Wk);
  k_attn<<<dim3(TC / 128, Bc, 4), 256, 0, stream>>>(xcat, e_t, e_ds, Op, Lp);
  k_norm<<<NBT / 4, 256, 0, stream>>>(Op, Lp, xcat);
  k_conv<<<dim3((TC / 32) * Bc), 256, 0, stream>>>(xcat, Wk, conv_b, out);
}

// Round 2
// 179.316 us; speedup vs baseline: 1.0369x; 1.0369x over previous
//
#include <hip/hip_runtime.h>

typedef __bf16 bf16x8 __attribute__((ext_vector_type(8)));
typedef __bf16 bf16x4 __attribute__((ext_vector_type(4)));
typedef float  f32x4  __attribute__((ext_vector_type(4)));

#define MFMA(a, b, c) __builtin_amdgcn_mfma_f32_16x16x32_bf16((a), (b), (c), 0, 0, 0)
// explicit DMA drain: vmcnt(0), leave expcnt/lgkmcnt unwaited (gfx9 encoding)
#define DRAIN_VMCNT() __builtin_amdgcn_s_waitcnt(0x0F70)

constexpr int Bc  = 8;
constexpr int D   = 256;
constexpr int TC  = 2048;
constexpr int TE  = 2048;
constexpr int TGT = 256;
constexpr int XR  = 256;            // xcat row stride (content half only now)
constexpr int NBT = Bc * TC;        // 16384 rows

// exp(x/16) == exp2(x * log2(e)/16)
#define EXP_C 0.09016844005556021f

// async global->LDS, 16B per lane; LDS dst = base + lane*16 (wave-uniform base),
// global source address is PER-LANE (m173 pattern: pre-swizzle the source).
__device__ __forceinline__ void gl_lds16(const __bf16* g, __bf16* l) {
  __builtin_amdgcn_global_load_lds(
      (const __attribute__((address_space(1))) void*)g,
      (__attribute__((address_space(3))) void*)l, 16, 0, 0);
}

// ---- fused prep: content transpose + emotion transpose/cast + weight repack ----
// grid (TC/64 + 1, 8, Bc):
//   x < 32, y < 4 : content fp32 [B][D][TC] -> xcat bf16 [B][TC][256]
//   x < 32, y >= 4: emotion fp32 [B][D][TE] -> e_t bf16 [B][TE][256] + e_ds copy
//   x == 32       : conv weight fp32 [256][512][3] -> Wk bf16 [3][256][512]
__global__ void k_prep_all(const float* __restrict__ content,
                           const float* __restrict__ emotion,
                           __bf16* __restrict__ xcat,
                           __bf16* __restrict__ e_t, __bf16* __restrict__ e_ds,
                           const float* __restrict__ w, __bf16* __restrict__ Wk) {
  __shared__ __bf16 tile[64][68];
  const int tid = threadIdx.x;

  if (blockIdx.x == TC / 64) {       // ---- weight repack: 64 blocks x 2048 idx ----
    const int base = (blockIdx.y * Bc + blockIdx.z) * 2048;
#pragma unroll
    for (int j = 0; j < 8; ++j) {
      const int idx = base + j * 256 + tid;   // o*512 + i
      const int o = idx >> 9, i = idx & 511;
#pragma unroll
      for (int k = 0; k < 3; ++k)
        Wk[k * (TGT * 512) + idx] = (__bf16)w[(size_t)o * 1536 + i * 3 + k];
    }
    return;
  }

  const bool isC = blockIdx.y < 4;
  const int b  = blockIdx.z;
  const int t0 = blockIdx.x * 64;
  const int d0 = (blockIdx.y & 3) * 64;
  const int c4 = (tid & 15) * 4;
  const int r0 = tid >> 4;          // 0..15
  const float* sp = (isC ? content : emotion) + ((size_t)b * D + d0) * 2048 + t0;
  __bf16* dsp = e_ds + ((size_t)b * D + d0) * TE + t0;   // used only if !isC
#pragma unroll
  for (int i = 0; i < 4; ++i) {
    const int r = r0 + 16 * i;
    const float4 v = *(const float4*)(sp + (size_t)r * 2048 + c4);
    bf16x4 pv;
    pv[0] = (__bf16)v.x; pv[1] = (__bf16)v.y; pv[2] = (__bf16)v.z; pv[3] = (__bf16)v.w;
    *(bf16x4*)&tile[r][c4] = pv;
    if (!isC) *(bf16x4*)(dsp + (size_t)r * TE + c4) = pv;
  }
  __syncthreads();
  // tile[d][t] -> dst rows t, 8 d per lane, 16B stores (both dst strides = 256)
  __bf16* dp = (isC ? xcat + ((size_t)b * TC + t0) * XR
                    : e_t + ((size_t)b * TE + t0) * D) + d0;
#pragma unroll
  for (int i = 0; i < 2; ++i) {
    const int idx = tid + 256 * i;  // 0..511
    const int r   = idx >> 3;       // output row (t-local) 0..63
    const int c8  = (idx & 7) * 8;  // output col block (d-local)
    bf16x8 v;
#pragma unroll
    for (int j = 0; j < 8; ++j) v[j] = tile[c8 + j][r];
    *(bf16x8*)(dp + (size_t)r * 256 + c8) = v;
  }
}

// ---- flash attention: 128 t x 4 waves (Tw=32), z=4 s-split, dbuf shared tiles ----
// All 4 waves consume the SAME 32-s tile pair; stage(k+1) issued before compute(k);
// vmcnt(0) drain at step end (issued a compute-phase ago -> hidden). Writes
// UNNORMALIZED bf16 partial O + fp32 partial L per z-chunk.
// NOTE: no s_setprio here — waves are barrier-lockstep, setprio measured -3.7us (R1).
__global__ __launch_bounds__(256, 2) void k_attn(const __bf16* __restrict__ xcat,
                                                 const __bf16* __restrict__ e_t,
                                                 const __bf16* __restrict__ e_ds,
                                                 __bf16* __restrict__ Op,
                                                 float* __restrict__ Lp) {
  __shared__ __align__(16) __bf16 sEt[2][8192];   // [buf]: row ss, chunk cs -> c=cs^(ss&7)
  __shared__ __align__(16) __bf16 sEs[2][8192];   // [buf]: row dd, slot ps -> p=ps^((dd>>2)&3)
  __shared__ __align__(16) __bf16 sP[4][2][640];  // per-wave P transpose, stride 40

  const int tid  = threadIdx.x;
  const int lane = tid & 63;
  const int w    = tid >> 6;        // 0..3 -> 32-t group
  const int q    = lane >> 4;
  const int tl   = lane & 15;
  const int b    = blockIdx.y;
  const int z    = blockIdx.z;      // s-quarter
  const int tbase = blockIdx.x * 128 + w * 32;

  const __bf16* etb = e_t  + (size_t)b * TE * D;   // [TE][D]
  const __bf16* esb = e_ds + (size_t)b * D * TE;   // [D][TE]

  // loop-invariant query fragments (B-operand of phase 1), 2 t-tiles
  bf16x8 cB[2][8];
#pragma unroll
  for (int tt = 0; tt < 2; ++tt) {
    const __bf16* crow = xcat + ((size_t)(b * TC) + tbase + tt * 16 + tl) * XR + q * 8;
#pragma unroll
    for (int ks = 0; ks < 8; ++ks) cB[tt][ks] = *(const bf16x8*)(crow + ks * 32);
  }

  // per-lane swizzled staging offsets; each wave stages 1/4 of each tile kind
  unsigned offEt[4], offEs[4];
#pragma unroll
  for (int c = 0; c < 4; ++c) {
    const int id = (w * 4 + c) * 64 + lane;        // 0..1023
    const int ss = id >> 5, cs = id & 31;
    offEt[c] = ss * D + (cs ^ (ss & 7)) * 8;       // row-contig global, swizzled chunk
    const int dd = id >> 2, ps = id & 3;
    offEs[c] = dd * TE + (ps ^ ((dd >> 2) & 3)) * 8;
  }

  f32x4 accO[2][16];
#pragma unroll
  for (int tt = 0; tt < 2; ++tt)
#pragma unroll
    for (int dt = 0; dt < 16; ++dt) accO[tt][dt] = (f32x4){0.f, 0.f, 0.f, 0.f};
  float lacc[2] = {0.f, 0.f};

  const int sbase = z * (TE / 4);
  const int sw3 = (tl >> 2) & 3;    // sEs read swizzle term

  auto stage = [&](int buf, int s0) {
#pragma unroll
    for (int c = 0; c < 4; ++c) {
      gl_lds16(etb + (size_t)s0 * D + offEt[c], &sEt[buf][(w * 4 + c) * 512]);
      gl_lds16(esb + s0 + offEs[c], &sEs[buf][(w * 4 + c) * 512]);
    }
  };

  stage(0, sbase);
  DRAIN_VMCNT();
  __syncthreads();

  int cur = 0;
  for (int k = 0; k < TE / 128; ++k) {   // 16 steps of 32 s
    if (k < TE / 128 - 1) stage(cur ^ 1, sbase + (k + 1) * 32);  // prefetch, in flight

    // ---- phase 1: S^T for 32 s x 32 t ----
    f32x4 aS[2][2];
#pragma unroll
    for (int i = 0; i < 2; ++i)
#pragma unroll
      for (int j = 0; j < 2; ++j) aS[i][j] = (f32x4){0.f, 0.f, 0.f, 0.f};
    const __bf16* pe = &sEt[cur][0];
#pragma unroll
    for (int ks = 0; ks < 8; ++ks) {
      const int ch = (ks * 4 + q) ^ (tl & 7);
      bf16x8 a0 = *(const bf16x8*)(pe + (tl * 32 + ch) * 8);
      bf16x8 a1 = *(const bf16x8*)(pe + ((16 + tl) * 32 + ch) * 8);
      aS[0][0] = MFMA(a0, cB[0][ks], aS[0][0]);
      aS[0][1] = MFMA(a0, cB[1][ks], aS[0][1]);
      aS[1][0] = MFMA(a1, cB[0][ks], aS[1][0]);
      aS[1][1] = MFMA(a1, cB[1][ks], aS[1][1]);
    }

    // ---- exp + pack bf16, C-layout -> per-wave LDS transpose ----
#pragma unroll
    for (int tt = 0; tt < 2; ++tt) {
      bf16x4 w0, w1;
#pragma unroll
      for (int r = 0; r < 4; ++r) {
        float e0 = exp2f(aS[0][tt][r] * EXP_C);
        float e1 = exp2f(aS[1][tt][r] * EXP_C);
        lacc[tt] += e0 + e1;
        w0[r] = (__bf16)e0;
        w1[r] = (__bf16)e1;
      }
      __bf16* pw = &sP[w][tt][tl * 40 + q * 4];
      *(bf16x4*)pw = w0;          // P[s=q*4+r][t=tl]
      *(bf16x4*)(pw + 16) = w1;   // P[s=16+q*4+r][t=tl]
    }
    bf16x8 pB0 = *(const bf16x8*)(&sP[w][0][tl * 40 + q * 8]);
    bf16x8 pB1 = *(const bf16x8*)(&sP[w][1][tl * 40 + q * 8]);

    // ---- phase 2: O^T accumulate, 16 d-tiles, A-frag shared by both t-tiles ----
    const __bf16* ps = &sEs[cur][0];
#pragma unroll
    for (int dt = 0; dt < 16; ++dt) {
      bf16x8 a = *(const bf16x8*)(ps + ((dt * 16 + tl) * 4 + (q ^ sw3)) * 8);
      accO[0][dt] = MFMA(a, pB0, accO[0][dt]);
      accO[1][dt] = MFMA(a, pB1, accO[1][dt]);
    }

    DRAIN_VMCNT();     // prefetch (issued before compute) must have landed
    __syncthreads();   // + all waves done reading tile k before overwrite
    cur ^= 1;
  }

  // ---- per-wave epilogue: no cross-wave merge (wave owns its 32 t) ----
#pragma unroll
  for (int tt = 0; tt < 2; ++tt) {
    float v = lacc[tt];
    v += __shfl_xor(v, 16, 64);
    v += __shfl_xor(v, 32, 64);
    const size_t row = (size_t)z * NBT + b * TC + tbase + tt * 16 + tl;
    if (q == 0) Lp[row] = v;
    __bf16* orow = Op + row * D + q * 4;
#pragma unroll
    for (int dt = 0; dt < 16; ++dt) {
      bf16x4 o;
#pragma unroll
      for (int r = 0; r < 4; ++r) o[r] = (__bf16)accO[tt][dt][r];
      *(bf16x4*)(orow + dt * 16) = o;
    }
  }
}

// ---- conv1d as LDS-staged 3-tap GEMM, with z-partial combine FUSED in ----
// 32 t x 256 o per block, grid 512, 2 blocks/CU. Input channels split into two
// 256-wide LDS planes: A = content (DMA, 2 rows/instr, source pre-swizzled),
// B = attention half (reg-staged from Op/Lp with on-the-fly normalize).
// Both planes: row t, 16B-chunk c holds X[t][c ^ (t&7)] -> 2-way max on reads.
__global__ __launch_bounds__(256, 2) void k_conv(const __bf16* __restrict__ xcat,
                                                 const __bf16* __restrict__ Op,
                                                 const float* __restrict__ Lp,
                                                 const __bf16* __restrict__ Wk,
                                                 const float* __restrict__ bias,
                                                 float* __restrict__ out) {
  __shared__ __align__(16) __bf16 sXA[34 * 256];   // content half, rows t0-1..t0+32
  __shared__ __align__(16) __bf16 sXB[34 * 256];   // normalized attn half
  __shared__ __align__(16) __bf16 sW[2][8192];     // row o, slot ps -> p=ps^((o>>2)&3)
  const int tid  = threadIdx.x;
  const int lane = tid & 63;
  const int wv   = tid >> 6;        // wave -> o-range (64 o each)
  const int q    = lane >> 4;
  const int tl   = lane & 15;
  const int b    = blockIdx.x & 7;
  const int t0   = (blockIdx.x >> 3) * 32;
  const int o0   = wv * 64;
  const int sw3  = (tl >> 2) & 3;
  const int rh   = lane >> 5;       // row-within-pair for staging
  const int l5   = lane & 31;

  // ---- plane A: DMA 2 rows per instruction, swizzled global source ----
  const __bf16* xb = xcat + (size_t)b * TC * XR;
  for (int i = wv; i < 17; i += 4) {
    const int rl = 2 * i + rh;                   // local row 0..33
    int gr = t0 - 1 + rl;
    gr = gr < 0 ? 0 : (gr > TC - 1 ? TC - 1 : gr);
    const int cs = l5 ^ (rl & 7);                // 16B-chunk index, pre-swizzled
    gl_lds16(xb + (size_t)gr * XR + cs * 8, &sXA[i * 512]);
  }

  // ---- weight staging offsets (swizzled, 64B-coalesced per o-row) ----
  unsigned offW[4];
#pragma unroll
  for (int c = 0; c < 4; ++c) {
    const int id = (wv * 4 + c) * 64 + lane;     // 0..1023
    const int o = id >> 2, ps = id & 3;
    offW[c] = o * 512 + (ps ^ ((o >> 2) & 3)) * 8;
  }
  auto stageW = [&](int buf, int s) {
    const int kk = s >> 4, is = s & 15;
    const __bf16* wb = Wk + (size_t)kk * TGT * 512 + is * 32;
#pragma unroll
    for (int c = 0; c < 4; ++c)
      gl_lds16(wb + offW[c], &sW[buf][(wv * 4 + c) * 512]);
  };
  stageW(0, 0);

  // ---- plane B: combine 4 z-partials + normalize, swizzled ds_write ----
  for (int i = wv; i < 17; i += 4) {
    const int rl = 2 * i + rh;
    int gr = t0 - 1 + rl;
    gr = gr < 0 ? 0 : (gr > TC - 1 ? TC - 1 : gr);
    const size_t row = (size_t)b * TC + gr;
    const float inv = 1.0f /
        (Lp[row] + Lp[NBT + row] + Lp[2 * NBT + row] + Lp[3 * NBT + row]);
    float a8[8] = {0.f, 0.f, 0.f, 0.f, 0.f, 0.f, 0.f, 0.f};
#pragma unroll
    for (int zz = 0; zz < 4; ++zz) {
      bf16x8 a = *(const bf16x8*)(Op + ((size_t)zz * NBT + row) * D + l5 * 8);
#pragma unroll
      for (int r = 0; r < 8; ++r) a8[r] += (float)a[r];
    }
    bf16x8 o;
#pragma unroll
    for (int r = 0; r < 8; ++r) o[r] = (__bf16)(a8[r] * inv);
    *(bf16x8*)((char*)&sXB[rl * 256] + ((l5 * 16) ^ ((rl & 7) << 4))) = o;
  }

  DRAIN_VMCNT();                    // plane A + sW(0) DMA landed
  __syncthreads();                  // (also drains lgkm for plane-B ds_writes)

  // halo rows: replace clamped duplicates with zeros (conv zero-padding)
  if (t0 == 0) {
    sXA[tid] = (__bf16)0.f; sXB[tid] = (__bf16)0.f;
    __syncthreads();
  }
  if (t0 + 32 == TC) {
    sXA[33 * 256 + tid] = (__bf16)0.f; sXB[33 * 256 + tid] = (__bf16)0.f;
    __syncthreads();
  }

  f32x4 acc[4][2];
#pragma unroll
  for (int mt = 0; mt < 4; ++mt) {
#pragma unroll
    for (int r = 0; r < 4; ++r) {
      const float bv = bias[o0 + mt * 16 + q * 4 + r];
#pragma unroll
      for (int nt = 0; nt < 2; ++nt) acc[mt][nt][r] = bv;
    }
  }

  int cur = 0;
  for (int s = 0; s < 48; ++s) {
    if (s < 47) stageW(cur ^ 1, s + 1);
    const int kk = s >> 4, is = s & 15;
    const __bf16* pl = (is & 8) ? sXB : sXA;     // ch 256:512 -> plane B
    const int cbyte = (is & 7) * 64 + q * 16;    // byte col base within plane
    bf16x8 bfr[2];
#pragma unroll
    for (int nt = 0; nt < 2; ++nt) {
      const int t = nt * 16 + tl + kk;
      bfr[nt] = *(const bf16x8*)((const char*)pl + t * 512 + (cbyte ^ ((t & 7) << 4)));
    }
#pragma unroll
    for (int mt = 0; mt < 4; ++mt) {
      const int o = o0 + mt * 16 + tl;
      bf16x8 af = *(const bf16x8*)(&sW[cur][(o * 4 + (q ^ sw3)) * 8]);
#pragma unroll
      for (int nt = 0; nt < 2; ++nt) acc[mt][nt] = MFMA(af, bfr[nt], acc[mt][nt]);
    }
    DRAIN_VMCNT();                  // next weight tile landed before buffer swap
    __syncthreads();
    cur ^= 1;
  }

#pragma unroll
  for (int mt = 0; mt < 4; ++mt) {
#pragma unroll
    for (int nt = 0; nt < 2; ++nt) {
#pragma unroll
      for (int r = 0; r < 4; ++r) {
        const int o = o0 + mt * 16 + q * 4 + r;
        const int t = t0 + nt * 16 + tl;
        out[((size_t)b * TGT + o) * TC + t] = acc[mt][nt][r];
      }
    }
  }
}

extern "C" void kernel_launch(void* const* d_in, const int* in_sizes, int n_in,
                              void* d_out, int out_size, void* d_ws, size_t ws_size,
                              hipStream_t stream) {
  (void)in_sizes; (void)n_in; (void)out_size; (void)ws_size;
  const float* content = (const float*)d_in[0];  // fp32 [B][256][2048]
  const float* emotion = (const float*)d_in[1];  // fp32 [B][256][2048]
  const float* conv_w  = (const float*)d_in[2];  // fp32 [256][512][3]
  const float* conv_b  = (const float*)d_in[3];  // fp32 [256]
  float* out = (float*)d_out;                    // fp32 [B][256][2048]

  char* ws = (char*)d_ws;
  __bf16* xcat = (__bf16*)ws;                          //  8,388,608 B
  __bf16* Wk   = (__bf16*)(ws + 8388608);              //    786,432 B
  __bf16* Op   = (__bf16*)(ws + 9437184);              // 33,554,432 B (4 z-partials)
  float*  Lp   = (float*)(ws + 42991616);              //    262,144 B (total 43.3 MB)
  // e_t + e_ds live in d_out (8,388,608 B each); consumed before k_conv writes out.
  __bf16* e_t  = (__bf16*)d_out;                       // bf16 [B][TE][D]
  __bf16* e_ds = (__bf16*)((char*)d_out + 8388608);    // bf16 [B][D][TE]

  k_prep_all<<<dim3(TC / 64 + 1, 8, Bc), 256, 0, stream>>>(
      content, emotion, xcat, e_t, e_ds, conv_w, Wk);
  k_attn<<<dim3(TC / 128, Bc, 4), 256, 0, stream>>>(xcat, e_t, e_ds, Op, Lp);
  k_conv<<<dim3((TC / 32) * Bc), 256, 0, stream>>>(xcat, Op, Lp, Wk, conv_b, out);
}

// Round 3
// 171.550 us; speedup vs baseline: 1.0838x; 1.0453x over previous
//
#include <hip/hip_runtime.h>

typedef __bf16 bf16x8 __attribute__((ext_vector_type(8)));
typedef __bf16 bf16x4 __attribute__((ext_vector_type(4)));
typedef float  f32x4  __attribute__((ext_vector_type(4)));

#define MFMA(a, b, c) __builtin_amdgcn_mfma_f32_16x16x32_bf16((a), (b), (c), 0, 0, 0)
// explicit DMA drain: vmcnt(0), leave expcnt/lgkmcnt unwaited (gfx9 encoding)
#define DRAIN_VMCNT() __builtin_amdgcn_s_waitcnt(0x0F70)

constexpr int Bc  = 8;
constexpr int D   = 256;
constexpr int TC  = 2048;
constexpr int TE  = 2048;
constexpr int TGT = 256;
constexpr int XR  = 256;            // xcat row stride (content half only)
constexpr int NBT = Bc * TC;        // 16384 rows

// exp(x/16) == exp2(x * log2(e)/16)
#define EXP_C 0.09016844005556021f

// async global->LDS, 16B per lane; LDS dst = base + lane*16 (wave-uniform base),
// global source address is PER-LANE (m173 pattern: pre-swizzle the source).
__device__ __forceinline__ void gl_lds16(const __bf16* g, __bf16* l) {
  __builtin_amdgcn_global_load_lds(
      (const __attribute__((address_space(1))) void*)g,
      (__attribute__((address_space(3))) void*)l, 16, 0, 0);
}

// ---- fused prep: content transpose + emotion transpose/cast + weight repack ----
// grid (TC/64 + 1, 8, Bc):
//   x < 32, y < 4 : content fp32 [B][D][TC] -> xcat bf16 [B][TC][256]
//   x < 32, y >= 4: emotion fp32 [B][D][TE] -> e_t bf16 [B][TE][256]
//                   + e_ds2 bf16 [B][64 s-tiles][256 d][32 s]  (4KB-contig chunks)
//   x == 32       : conv weight fp32 [256][512][3] -> Wk bf16 [3][256][512]
__global__ void k_prep_all(const float* __restrict__ content,
                           const float* __restrict__ emotion,
                           __bf16* __restrict__ xcat,
                           __bf16* __restrict__ e_t, __bf16* __restrict__ e_ds2,
                           const float* __restrict__ w, __bf16* __restrict__ Wk) {
  __shared__ __bf16 tile[64][68];
  const int tid = threadIdx.x;

  if (blockIdx.x == TC / 64) {       // ---- weight repack: 64 blocks x 2048 idx ----
    const int base = (blockIdx.y * Bc + blockIdx.z) * 2048;
#pragma unroll
    for (int j = 0; j < 8; ++j) {
      const int idx = base + j * 256 + tid;   // o*512 + i
      const int o = idx >> 9, i = idx & 511;
#pragma unroll
      for (int k = 0; k < 3; ++k)
        Wk[k * (TGT * 512) + idx] = (__bf16)w[(size_t)o * 1536 + i * 3 + k];
    }
    return;
  }

  const bool isC = blockIdx.y < 4;
  const int b  = blockIdx.z;
  const int t0 = blockIdx.x * 64;
  const int d0 = (blockIdx.y & 3) * 64;
  const int c4 = (tid & 15) * 4;
  const int r0 = tid >> 4;          // 0..15
  const float* sp = (isC ? content : emotion) + ((size_t)b * D + d0) * 2048 + t0;
#pragma unroll
  for (int i = 0; i < 4; ++i) {
    const int r = r0 + 16 * i;
    const float4 v = *(const float4*)(sp + (size_t)r * 2048 + c4);
    bf16x4 pv;
    pv[0] = (__bf16)v.x; pv[1] = (__bf16)v.y; pv[2] = (__bf16)v.z; pv[3] = (__bf16)v.w;
    *(bf16x4*)&tile[r][c4] = pv;
  }
  __syncthreads();

  // tile[d][t] -> transposed dst rows t, 8 d per lane, 16B stores (stride 256)
  __bf16* dp = (isC ? xcat + ((size_t)b * TC + t0) * XR
                    : e_t + ((size_t)b * TE + t0) * D) + d0;
#pragma unroll
  for (int i = 0; i < 2; ++i) {
    const int idx = tid + 256 * i;  // 0..511
    const int r   = idx >> 3;       // output row (t-local) 0..63
    const int c8  = (idx & 7) * 8;  // output col block (d-local)
    bf16x8 v;
#pragma unroll
    for (int j = 0; j < 8; ++j) v[j] = tile[c8 + j][r];
    *(bf16x8*)(dp + (size_t)r * 256 + c8) = v;
  }

  // e_ds2: row-major LDS reads (2x b64), fully-contiguous 4KB global chunks
  if (!isC) {
    const int row = tid >> 2, sc = tid & 3;   // d-local row, 16B chunk in 32-s
#pragma unroll
    for (int h = 0; h < 2; ++h) {
      bf16x4 lo = *(const bf16x4*)&tile[row][h * 32 + sc * 8];
      bf16x4 hi = *(const bf16x4*)&tile[row][h * 32 + sc * 8 + 4];
      bf16x8 v;
      v[0] = lo[0]; v[1] = lo[1]; v[2] = lo[2]; v[3] = lo[3];
      v[4] = hi[0]; v[5] = hi[1]; v[6] = hi[2]; v[7] = hi[3];
      __bf16* qp = e_ds2 +
          ((((size_t)b * 64 + (t0 >> 5) + h) * 256 + d0 + row) << 5) + sc * 8;
      *(bf16x8*)qp = v;
    }
  }
}

// ---- flash attention: 128 t x 4 waves (Tw=32), z=4 s-split, dbuf shared tiles ----
// XCD-pinned: hw XCD = blockIdx.x % 8 (grid.x=16 round-robin), so logical b = x&7
// puts all 64 blocks (4 z x 16 t-blocks) of one batch on ONE XCD -> per-XCD L2
// working set ~3MB (e_t[b] + e_ds2[b] + xcat[b]) fits 4MB L2, kills 8x fetch dup.
// All 4 waves consume the SAME 32-s tile pair; stage(k+1) issued before compute(k);
// vmcnt(0) drain at step end (issued a compute-phase ago -> hidden). Writes
// UNNORMALIZED bf16 partial O + fp32 partial L per z-chunk.
// NOTE: no s_setprio — waves are barrier-lockstep, setprio measured -3.7us (R1).
__global__ __launch_bounds__(256, 2) void k_attn(const __bf16* __restrict__ xcat,
                                                 const __bf16* __restrict__ e_t,
                                                 const __bf16* __restrict__ e_ds2,
                                                 __bf16* __restrict__ Op,
                                                 float* __restrict__ Lp) {
  __shared__ __align__(16) __bf16 sEt[2][8192];   // [buf]: row ss, chunk cs -> c=cs^(ss&7)
  __shared__ __align__(16) __bf16 sEs[2][8192];   // [buf]: row dd, slot ps -> p=ps^((dd>>2)&3)
  __shared__ __align__(16) __bf16 sP[4][2][640];  // per-wave P transpose, stride 40

  const int tid  = threadIdx.x;
  const int lane = tid & 63;
  const int w    = tid >> 6;        // 0..3 -> 32-t group
  const int q    = lane >> 4;
  const int tl   = lane & 15;
  const int b    = blockIdx.x & 7;                          // XCD-pinned batch
  const int xt   = (blockIdx.x >> 3) | (blockIdx.y << 1);   // logical t-block 0..15
  const int z    = blockIdx.z;      // s-quarter
  const int tbase = xt * 128 + w * 32;

  const __bf16* etb  = e_t  + (size_t)b * TE * D;     // [TE][D]
  const __bf16* esb2 = e_ds2 + (size_t)b * 64 * 8192; // [64 tiles][8192]

  // loop-invariant query fragments (B-operand of phase 1), 2 t-tiles
  bf16x8 cB[2][8];
#pragma unroll
  for (int tt = 0; tt < 2; ++tt) {
    const __bf16* crow = xcat + ((size_t)(b * TC) + tbase + tt * 16 + tl) * XR + q * 8;
#pragma unroll
    for (int ks = 0; ks < 8; ++ks) cB[tt][ks] = *(const bf16x8*)(crow + ks * 32);
  }

  // per-lane swizzled staging offsets; each wave stages 1/4 of each tile kind
  unsigned offEt[4], offEs[4];
#pragma unroll
  for (int c = 0; c < 4; ++c) {
    const int id = (w * 4 + c) * 64 + lane;        // 0..1023
    const int ss = id >> 5, cs = id & 31;
    offEt[c] = ss * D + (cs ^ (ss & 7)) * 8;       // row-contig global, swizzled chunk
    const int dd = id >> 2, ps = id & 3;
    offEs[c] = dd * 32 + (ps ^ ((dd >> 2) & 3)) * 8;  // tile-local, contiguous tile
  }

  f32x4 accO[2][16];
#pragma unroll
  for (int tt = 0; tt < 2; ++tt)
#pragma unroll
    for (int dt = 0; dt < 16; ++dt) accO[tt][dt] = (f32x4){0.f, 0.f, 0.f, 0.f};
  float lacc[2] = {0.f, 0.f};

  const int sbase = z * (TE / 4);
  const int sw3 = (tl >> 2) & 3;    // sEs read swizzle term

  auto stage = [&](int buf, int s0) {
    const __bf16* et = etb + (size_t)s0 * D;
    const __bf16* es = esb2 + ((size_t)(s0 >> 5)) * 8192;
#pragma unroll
    for (int c = 0; c < 4; ++c) {
      gl_lds16(et + offEt[c], &sEt[buf][(w * 4 + c) * 512]);
      gl_lds16(es + offEs[c], &sEs[buf][(w * 4 + c) * 512]);
    }
  };

  stage(0, sbase);
  DRAIN_VMCNT();
  __syncthreads();

  int cur = 0;
  for (int k = 0; k < TE / 128; ++k) {   // 16 steps of 32 s
    if (k < TE / 128 - 1) stage(cur ^ 1, sbase + (k + 1) * 32);  // prefetch, in flight

    // ---- phase 1: S^T for 32 s x 32 t ----
    f32x4 aS[2][2];
#pragma unroll
    for (int i = 0; i < 2; ++i)
#pragma unroll
      for (int j = 0; j < 2; ++j) aS[i][j] = (f32x4){0.f, 0.f, 0.f, 0.f};
    const __bf16* pe = &sEt[cur][0];
#pragma unroll
    for (int ks = 0; ks < 8; ++ks) {
      const int ch = (ks * 4 + q) ^ (tl & 7);
      bf16x8 a0 = *(const bf16x8*)(pe + (tl * 32 + ch) * 8);
      bf16x8 a1 = *(const bf16x8*)(pe + ((16 + tl) * 32 + ch) * 8);
      aS[0][0] = MFMA(a0, cB[0][ks], aS[0][0]);
      aS[0][1] = MFMA(a0, cB[1][ks], aS[0][1]);
      aS[1][0] = MFMA(a1, cB[0][ks], aS[1][0]);
      aS[1][1] = MFMA(a1, cB[1][ks], aS[1][1]);
    }

    // ---- exp + pack bf16, C-layout -> per-wave LDS transpose ----
#pragma unroll
    for (int tt = 0; tt < 2; ++tt) {
      bf16x4 w0, w1;
#pragma unroll
      for (int r = 0; r < 4; ++r) {
        float e0 = exp2f(aS[0][tt][r] * EXP_C);
        float e1 = exp2f(aS[1][tt][r] * EXP_C);
        lacc[tt] += e0 + e1;
        w0[r] = (__bf16)e0;
        w1[r] = (__bf16)e1;
      }
      __bf16* pw = &sP[w][tt][tl * 40 + q * 4];
      *(bf16x4*)pw = w0;          // P[s=q*4+r][t=tl]
      *(bf16x4*)(pw + 16) = w1;   // P[s=16+q*4+r][t=tl]
    }
    bf16x8 pB0 = *(const bf16x8*)(&sP[w][0][tl * 40 + q * 8]);
    bf16x8 pB1 = *(const bf16x8*)(&sP[w][1][tl * 40 + q * 8]);

    // ---- phase 2: O^T accumulate, 16 d-tiles, A-frag shared by both t-tiles ----
    const __bf16* ps = &sEs[cur][0];
#pragma unroll
    for (int dt = 0; dt < 16; ++dt) {
      bf16x8 a = *(const bf16x8*)(ps + ((dt * 16 + tl) * 4 + (q ^ sw3)) * 8);
      accO[0][dt] = MFMA(a, pB0, accO[0][dt]);
      accO[1][dt] = MFMA(a, pB1, accO[1][dt]);
    }

    DRAIN_VMCNT();     // prefetch (issued before compute) must have landed
    __syncthreads();   // + all waves done reading tile k before overwrite
    cur ^= 1;
  }

  // ---- per-wave epilogue: no cross-wave merge (wave owns its 32 t) ----
#pragma unroll
  for (int tt = 0; tt < 2; ++tt) {
    float v = lacc[tt];
    v += __shfl_xor(v, 16, 64);
    v += __shfl_xor(v, 32, 64);
    const size_t row = (size_t)z * NBT + b * TC + tbase + tt * 16 + tl;
    if (q == 0) Lp[row] = v;
    __bf16* orow = Op + row * D + q * 4;
#pragma unroll
    for (int dt = 0; dt < 16; ++dt) {
      bf16x4 o;
#pragma unroll
      for (int r = 0; r < 4; ++r) o[r] = (__bf16)accO[tt][dt][r];
      *(bf16x4*)(orow + dt * 16) = o;
    }
  }
}

// ---- conv1d as LDS-staged 3-tap GEMM, with z-partial combine FUSED in ----
// 32 t x 256 o per block, grid 512, 2 blocks/CU. Input channels split into two
// 256-wide LDS planes: A = content (DMA, 2 rows/instr, source pre-swizzled),
// B = attention half (reg-staged from Op/Lp with on-the-fly normalize).
// Both planes: row t, 16B-chunk c holds X[t][c ^ (t&7)] -> 2-way max on reads.
__global__ __launch_bounds__(256, 2) void k_conv(const __bf16* __restrict__ xcat,
                                                 const __bf16* __restrict__ Op,
                                                 const float* __restrict__ Lp,
                                                 const __bf16* __restrict__ Wk,
                                                 const float* __restrict__ bias,
                                                 float* __restrict__ out) {
  __shared__ __align__(16) __bf16 sXA[34 * 256];   // content half, rows t0-1..t0+32
  __shared__ __align__(16) __bf16 sXB[34 * 256];   // normalized attn half
  __shared__ __align__(16) __bf16 sW[2][8192];     // row o, slot ps -> p=ps^((o>>2)&3)
  const int tid  = threadIdx.x;
  const int lane = tid & 63;
  const int wv   = tid >> 6;        // wave -> o-range (64 o each)
  const int q    = lane >> 4;
  const int tl   = lane & 15;
  const int b    = blockIdx.x & 7;
  const int t0   = (blockIdx.x >> 3) * 32;
  const int o0   = wv * 64;
  const int sw3  = (tl >> 2) & 3;
  const int rh   = lane >> 5;       // row-within-pair for staging
  const int l5   = lane & 31;

  // ---- plane A: DMA 2 rows per instruction, swizzled global source ----
  const __bf16* xb = xcat + (size_t)b * TC * XR;
  for (int i = wv; i < 17; i += 4) {
    const int rl = 2 * i + rh;                   // local row 0..33
    int gr = t0 - 1 + rl;
    gr = gr < 0 ? 0 : (gr > TC - 1 ? TC - 1 : gr);
    const int cs = l5 ^ (rl & 7);                // 16B-chunk index, pre-swizzled
    gl_lds16(xb + (size_t)gr * XR + cs * 8, &sXA[i * 512]);
  }

  // ---- weight staging offsets (swizzled, 64B-coalesced per o-row) ----
  unsigned offW[4];
#pragma unroll
  for (int c = 0; c < 4; ++c) {
    const int id = (wv * 4 + c) * 64 + lane;     // 0..1023
    const int o = id >> 2, ps = id & 3;
    offW[c] = o * 512 + (ps ^ ((o >> 2) & 3)) * 8;
  }
  auto stageW = [&](int buf, int s) {
    const int kk = s >> 4, is = s & 15;
    const __bf16* wb = Wk + (size_t)kk * TGT * 512 + is * 32;
#pragma unroll
    for (int c = 0; c < 4; ++c)
      gl_lds16(wb + offW[c], &sW[buf][(wv * 4 + c) * 512]);
  };
  stageW(0, 0);

  // ---- plane B: combine 4 z-partials + normalize, swizzled ds_write ----
  for (int i = wv; i < 17; i += 4) {
    const int rl = 2 * i + rh;
    int gr = t0 - 1 + rl;
    gr = gr < 0 ? 0 : (gr > TC - 1 ? TC - 1 : gr);
    const size_t row = (size_t)b * TC + gr;
    const float inv = 1.0f /
        (Lp[row] + Lp[NBT + row] + Lp[2 * NBT + row] + Lp[3 * NBT + row]);
    float a8[8] = {0.f, 0.f, 0.f, 0.f, 0.f, 0.f, 0.f, 0.f};
#pragma unroll
    for (int zz = 0; zz < 4; ++zz) {
      bf16x8 a = *(const bf16x8*)(Op + ((size_t)zz * NBT + row) * D + l5 * 8);
#pragma unroll
      for (int r = 0; r < 8; ++r) a8[r] += (float)a[r];
    }
    bf16x8 o;
#pragma unroll
    for (int r = 0; r < 8; ++r) o[r] = (__bf16)(a8[r] * inv);
    *(bf16x8*)((char*)&sXB[rl * 256] + ((l5 * 16) ^ ((rl & 7) << 4))) = o;
  }

  DRAIN_VMCNT();                    // plane A + sW(0) DMA landed
  __syncthreads();                  // (also drains lgkm for plane-B ds_writes)

  // halo rows: replace clamped duplicates with zeros (conv zero-padding)
  if (t0 == 0) {
    sXA[tid] = (__bf16)0.f; sXB[tid] = (__bf16)0.f;
    __syncthreads();
  }
  if (t0 + 32 == TC) {
    sXA[33 * 256 + tid] = (__bf16)0.f; sXB[33 * 256 + tid] = (__bf16)0.f;
    __syncthreads();
  }

  f32x4 acc[4][2];
#pragma unroll
  for (int mt = 0; mt < 4; ++mt) {
#pragma unroll
    for (int r = 0; r < 4; ++r) {
      const float bv = bias[o0 + mt * 16 + q * 4 + r];
#pragma unroll
      for (int nt = 0; nt < 2; ++nt) acc[mt][nt][r] = bv;
    }
  }

  int cur = 0;
  for (int s = 0; s < 48; ++s) {
    if (s < 47) stageW(cur ^ 1, s + 1);
    const int kk = s >> 4, is = s & 15;
    const __bf16* pl = (is & 8) ? sXB : sXA;     // ch 256:512 -> plane B
    const int cbyte = (is & 7) * 64 + q * 16;    // byte col base within plane
    bf16x8 bfr[2];
#pragma unroll
    for (int nt = 0; nt < 2; ++nt) {
      const int t = nt * 16 + tl + kk;
      bfr[nt] = *(const bf16x8*)((const char*)pl + t * 512 + (cbyte ^ ((t & 7) << 4)));
    }
#pragma unroll
    for (int mt = 0; mt < 4; ++mt) {
      const int o = o0 + mt * 16 + tl;
      bf16x8 af = *(const bf16x8*)(&sW[cur][(o * 4 + (q ^ sw3)) * 8]);
#pragma unroll
      for (int nt = 0; nt < 2; ++nt) acc[mt][nt] = MFMA(af, bfr[nt], acc[mt][nt]);
    }
    DRAIN_VMCNT();                  // next weight tile landed before buffer swap
    __syncthreads();
    cur ^= 1;
  }

#pragma unroll
  for (int mt = 0; mt < 4; ++mt) {
#pragma unroll
    for (int nt = 0; nt < 2; ++nt) {
#pragma unroll
      for (int r = 0; r < 4; ++r) {
        const int o = o0 + mt * 16 + q * 4 + r;
        const int t = t0 + nt * 16 + tl;
        out[((size_t)b * TGT + o) * TC + t] = acc[mt][nt][r];
      }
    }
  }
}

extern "C" void kernel_launch(void* const* d_in, const int* in_sizes, int n_in,
                              void* d_out, int out_size, void* d_ws, size_t ws_size,
                              hipStream_t stream) {
  (void)in_sizes; (void)n_in; (void)out_size; (void)ws_size;
  const float* content = (const float*)d_in[0];  // fp32 [B][256][2048]
  const float* emotion = (const float*)d_in[1];  // fp32 [B][256][2048]
  const float* conv_w  = (const float*)d_in[2];  // fp32 [256][512][3]
  const float* conv_b  = (const float*)d_in[3];  // fp32 [256]
  float* out = (float*)d_out;                    // fp32 [B][256][2048]

  char* ws = (char*)d_ws;
  __bf16* xcat = (__bf16*)ws;                          //  8,388,608 B
  __bf16* Wk   = (__bf16*)(ws + 8388608);              //    786,432 B
  __bf16* Op   = (__bf16*)(ws + 9437184);              // 33,554,432 B (4 z-partials)
  float*  Lp   = (float*)(ws + 42991616);              //    262,144 B (total 43.3 MB)
  // e_t + e_ds2 live in d_out (8,388,608 B each); consumed before k_conv writes out.
  __bf16* e_t   = (__bf16*)d_out;                      // bf16 [B][TE][D]
  __bf16* e_ds2 = (__bf16*)((char*)d_out + 8388608);   // bf16 [B][64][256][32]

  k_prep_all<<<dim3(TC / 64 + 1, 8, Bc), 256, 0, stream>>>(
      content, emotion, xcat, e_t, e_ds2, conv_w, Wk);
  k_attn<<<dim3(TC / 128, Bc, 4), 256, 0, stream>>>(xcat, e_t, e_ds2, Op, Lp);
  k_conv<<<dim3((TC / 32) * Bc), 256, 0, stream>>>(xcat, Op, Lp, Wk, conv_b, out);
}